// Round 7
// baseline (1052.273 us; speedup 1.0000x reference)
//
#include <hip/hip_runtime.h>
#include <cstdint>

#define B_SZ 4096
#define T_SZ 1000
#define I_SZ 3
#define H_SZ 10
#define GPW  6          // batch groups per wave (10 lanes each; lanes 60-63 dummy)

// LDS weight tables: 16 tables x 10 rows x 12 words (48B rows -> ds offsets fold).
// Tables 0..14 = (mat, gate), mat: 0=Whh0 1=Wih1 2=Whh1 3=Wih2 4=Whh2.
//   Row u, words 0..9 = M[gate*10+u][0..9], words 10,11 = 0 (pad, FMA-safe).
// Table 15 = Wih0: row u, words gate*4+{0,1,2} = Wih0[(gate*10+u)*3+i], +3 = 0.
// Row addr = u*48B: bank starts 12u mod 32 tile all 32 banks, only u=8,9 alias
// u=0,1 -> 2-way max (free, m136). 6-7 lanes share each addr -> broadcast.
#define NW_WORDS (16 * 120)
#define SH_WORDS (3 * 84)   // h planes [layer][g*12 + j]; reads conflict-free

__device__ __forceinline__ float fsig(float s) {
    float e = __expf(-s);                       // s<<0 -> inf -> rcp 0; s>>0 -> 1
    return __builtin_amdgcn_rcpf(1.0f + e);
}
__device__ __forceinline__ float ftanh(float y) {
    float e2 = __expf(y + y);                   // inf-safe both ends
    return 1.0f - 2.0f * __builtin_amdgcn_rcpf(e2 + 1.0f);
}

#define LDW(m, g, c) (*(const float4*)(wp + (((m)*3 + (g))*480 + (c)*16)))
#define FMA4(Q, H, acc) \
    acc = fmaf((Q).x, (H).x, acc); acc = fmaf((Q).y, (H).y, acc); \
    acc = fmaf((Q).z, (H).z, acc); acc = fmaf((Q).w, (H).w, acc);

// One K-chunk (4 k-values): 15 ds_read_b128 + 60 FMAs over 15 disjoint chains.
#define WCHUNK(c, HA, HB, HC) do { \
    const float4 Q00=LDW(0,0,c), Q01=LDW(0,1,c), Q02=LDW(0,2,c); \
    const float4 Q10=LDW(1,0,c), Q11=LDW(1,1,c), Q12=LDW(1,2,c); \
    const float4 Q20=LDW(2,0,c), Q21=LDW(2,1,c), Q22=LDW(2,2,c); \
    const float4 Q30=LDW(3,0,c), Q31=LDW(3,1,c), Q32=LDW(3,2,c); \
    const float4 Q40=LDW(4,0,c), Q41=LDW(4,1,c), Q42=LDW(4,2,c); \
    FMA4(Q00, HA, r0)  FMA4(Q01, HA, z0)  FMA4(Q02, HA, nh0) \
    FMA4(Q10, HA, ri1) FMA4(Q11, HA, zi1) FMA4(Q12, HA, nx1) \
    FMA4(Q20, HB, rh1) FMA4(Q21, HB, zh1) FMA4(Q22, HB, nh1) \
    FMA4(Q30, HB, ri2) FMA4(Q31, HB, zi2) FMA4(Q32, HB, nx2) \
    FMA4(Q40, HC, rh2) FMA4(Q41, HC, zh2) FMA4(Q42, HC, nh2) \
} while (0)

__global__ __launch_bounds__(64, 1) void gru3_ldsw(
    const float* __restrict__ x,
    const float* __restrict__ Wih0, const float* __restrict__ Whh0,
    const float* __restrict__ bih0, const float* __restrict__ bhh0,
    const float* __restrict__ Wih1, const float* __restrict__ Whh1,
    const float* __restrict__ bih1, const float* __restrict__ bhh1,
    const float* __restrict__ Wih2, const float* __restrict__ Whh2,
    const float* __restrict__ bih2, const float* __restrict__ bhh2,
    const float* __restrict__ Wout, const float* __restrict__ bout,
    float* __restrict__ out)
{
    __shared__ __align__(16) float sw[NW_WORDS];
    __shared__ __align__(16) float sh[SH_WORDS];

    const int lane  = threadIdx.x;     // block = 1 wave
    const int j     = lane % H_SZ;     // hidden unit 0..9
    const int g     = lane / H_SZ;     // group 0..6 (6 = dummy)
    const int b_raw = blockIdx.x * GPW + g;
    const int b     = b_raw < B_SZ ? b_raw : (B_SZ - 1);

    // ---- stage weights into LDS (once; ~1.6K elems over 64 lanes) ----
    for (int t = lane; t < 300; t += 64) { int r=t/10,k=t%10,gg=r/10,u=r%10; sw[(0*3+gg)*120 + u*12 + k] = Whh0[t]; }
    for (int t = lane; t < 300; t += 64) { int r=t/10,k=t%10,gg=r/10,u=r%10; sw[(1*3+gg)*120 + u*12 + k] = Wih1[t]; }
    for (int t = lane; t < 300; t += 64) { int r=t/10,k=t%10,gg=r/10,u=r%10; sw[(2*3+gg)*120 + u*12 + k] = Whh1[t]; }
    for (int t = lane; t < 300; t += 64) { int r=t/10,k=t%10,gg=r/10,u=r%10; sw[(3*3+gg)*120 + u*12 + k] = Wih2[t]; }
    for (int t = lane; t < 300; t += 64) { int r=t/10,k=t%10,gg=r/10,u=r%10; sw[(4*3+gg)*120 + u*12 + k] = Whh2[t]; }
    for (int t = lane; t < 90;  t += 64) { int r=t/3, i=t%3, gg=r/10,u=r%10; sw[15*120 + u*12 + gg*4 + i] = Wih0[t]; }
    for (int t = lane; t < 150; t += 64) { int tab=t/10,u=t%10; sw[tab*120 + u*12 + 10] = 0.f; sw[tab*120 + u*12 + 11] = 0.f; }
    for (int t = lane; t < 30;  t += 64) { int u=t/3, c=t%3; sw[15*120 + u*12 + c*4 + 3] = 0.f; }
    for (int t = lane; t < SH_WORDS; t += 64) sh[t] = 0.0f;   // h planes = 0
    __syncthreads();

    // ---- biases (12 scalars; only long-lived registers besides y/h) ----
    const float br0 = bih0[j] + bhh0[j], bz0 = bih0[10 + j] + bhh0[10 + j];
    const float bni0 = bih0[20 + j], bnh0 = bhh0[20 + j];
    const float br1 = bih1[j] + bhh1[j], bz1 = bih1[10 + j] + bhh1[10 + j];
    const float bni1 = bih1[20 + j], bnh1 = bhh1[20 + j];
    const float br2 = bih2[j] + bhh2[j], bz2 = bih2[10 + j] + bhh2[10 + j];
    const float bni2 = bih2[20 + j], bnh2 = bhh2[20 + j];

    float y0 = 0.0f, y1 = 0.0f, y2 = 0.0f;   // this lane's own h elements

    const float* xp = x + (size_t)b * (T_SZ * I_SZ);
    float cx0 = xp[0], cx1 = xp[1], cx2 = xp[2];   // x[t] prefetch regs

    const float4* pa = reinterpret_cast<const float4*>(&sh[g * 12]);         // h0
    const float4* pb = reinterpret_cast<const float4*>(&sh[84 + g * 12]);    // h1
    const float4* pc = reinterpret_cast<const float4*>(&sh[168 + g * 12]);   // h2
    float4 Aq0 = pa[0], Aq1 = pa[1], Aq2 = pa[2];
    float4 Bq0 = pb[0], Bq1 = pb[1], Bq2 = pb[2];
    float4 Cq0 = pc[0], Cq1 = pc[1], Cq2 = pc[2];

    int aw = j * 48;                    // per-lane weight row byte-offset

    // iter it: L0@t=it, L1@t=it-1, L2@t=it-2 (layer-pipelined, barrier-free).
#pragma unroll 1
    for (int it = 0; it < T_SZ + 2; ++it) {
        // Pin the LDS weight base each iteration: blocks LICM from hoisting the
        // 48 ds_reads out of the loop (which would recreate the 159-live-value
        // spill problem R2-R6 all hit). All read offsets fold into ds imm.
        asm volatile("" : "+v"(aw));
        const char* wp = (const char*)sw + aw;

        const float x0 = cx0, x1 = cx1, x2 = cx2;
        const int tn = (it + 1 < T_SZ) ? it + 1 : (T_SZ - 1);
        cx0 = xp[tn * 3 + 0];           // prefetch next x under this body
        cx1 = xp[tn * 3 + 1];
        cx2 = xp[tn * 3 + 2];

        // ---- 16 independent accumulator chains ----
        float r0 = br0, z0 = bz0, nx0 = bni0, nh0 = bnh0;
        float ri1 = br1, rh1 = 0.f, zi1 = bz1, zh1 = 0.f, nx1 = bni1, nh1 = bnh1;
        float ri2 = br2, rh2 = 0.f, zi2 = bz2, zh2 = 0.f, nx2 = bni2, nh2 = bnh2;

        // L0 x-dot from table 15
        {
            const float4 P0 = *(const float4*)(wp + 15 * 480);
            const float4 P1 = *(const float4*)(wp + 15 * 480 + 16);
            const float4 P2 = *(const float4*)(wp + 15 * 480 + 32);
            r0  = fmaf(P0.x, x0, r0);  r0  = fmaf(P0.y, x1, r0);  r0  = fmaf(P0.z, x2, r0);
            z0  = fmaf(P1.x, x0, z0);  z0  = fmaf(P1.y, x1, z0);  z0  = fmaf(P1.z, x2, z0);
            nx0 = fmaf(P2.x, x0, nx0); nx0 = fmaf(P2.y, x1, nx0); nx0 = fmaf(P2.z, x2, nx0);
        }

        WCHUNK(0, Aq0, Bq0, Cq0);
        WCHUNK(1, Aq1, Bq1, Cq1);
        WCHUNK(2, Aq2, Bq2, Cq2);      // k=8,9 real; 10,11 hit zero pads (safe)

        // ---- gates (18 trans, 9 independent chains) ----
        const float R0 = fsig(r0),        Z0 = fsig(z0);
        const float R1 = fsig(ri1 + rh1), Z1 = fsig(zi1 + zh1);
        const float R2 = fsig(ri2 + rh2), Z2 = fsig(zi2 + zh2);
        const float N0 = ftanh(fmaf(R0, nh0, nx0));
        const float N1 = ftanh(fmaf(R1, nh1, nx1));
        const float N2 = ftanh(fmaf(R2, nh2, nx2));

        const float t0 = fmaf(Z0, y0 - N0, N0);
        const float t1 = fmaf(Z1, y1 - N1, N1);
        const float t2 = fmaf(Z2, y2 - N2, N2);
        y0 = (it < T_SZ)             ? t0 : y0;   // branch-free commits
        y1 = (it >= 1 && it <= T_SZ) ? t1 : y1;
        y2 = (it >= 2)               ? t2 : y2;

        sh[g * 12 + j]       = y0;
        sh[84 + g * 12 + j]  = y1;
        sh[168 + g * 12 + j] = y2;

        // rotate: next iteration's h reads issue under the loop tail
        Aq0 = pa[0]; Aq1 = pa[1]; Aq2 = pa[2];
        Bq0 = pb[0]; Bq1 = pb[1]; Bq2 = pb[2];
        Cq0 = pc[0]; Cq1 = pc[1]; Cq2 = pc[2];
    }

    // ---- output projection: out[b] = h2(T-1) . Wout + bout ----
    if (j == 0 && g < GPW && b_raw < B_SZ) {
        const float* hv = &sh[168 + g * 12];
        float acc = bout[0];
#pragma unroll
        for (int k = 0; k < H_SZ; ++k) acc = fmaf(hv[k], Wout[k], acc);
        out[b_raw] = acc;
    }
}

extern "C" void kernel_launch(void* const* d_in, const int* in_sizes, int n_in,
                              void* d_out, int out_size, void* d_ws, size_t ws_size,
                              hipStream_t stream) {
    const float* x    = (const float*)d_in[0];
    const float* Wih0 = (const float*)d_in[1];
    const float* Whh0 = (const float*)d_in[2];
    const float* bih0 = (const float*)d_in[3];
    const float* bhh0 = (const float*)d_in[4];
    const float* Wih1 = (const float*)d_in[5];
    const float* Whh1 = (const float*)d_in[6];
    const float* bih1 = (const float*)d_in[7];
    const float* bhh1 = (const float*)d_in[8];
    const float* Wih2 = (const float*)d_in[9];
    const float* Whh2 = (const float*)d_in[10];
    const float* bih2 = (const float*)d_in[11];
    const float* bhh2 = (const float*)d_in[12];
    const float* Wout = (const float*)d_in[13];
    const float* bout = (const float*)d_in[14];
    float* out = (float*)d_out;

    const int grid = (B_SZ + GPW - 1) / GPW;   // 683 single-wave blocks
    gru3_ldsw<<<grid, 64, 0, stream>>>(x, Wih0, Whh0, bih0, bhh0,
                                       Wih1, Whh1, bih1, bhh1,
                                       Wih2, Whh2, bih2, bhh2,
                                       Wout, bout, out);
}

// Round 8
// 620.948 us; speedup vs baseline: 1.6946x; 1.6946x over previous
//
#include <hip/hip_runtime.h>
#include <cstdint>

#define B_SZ 4096
#define T_SZ 1000
#define I_SZ 3
#define H_SZ 10
#define GPW  6            // batch groups per wave (10 lanes each; lanes 60-63 dummy)
#define STRIDE 36         // words per group (3 slots x 12); 7 groups' float4 reads
                          // start at banks {0,4,8,...}: disjoint 4-bank spans.

__device__ __forceinline__ float fsig(float s) {
    float e = __expf(-s);                       // s<<0 -> inf -> rcp 0; s>>0 -> 1
    return __builtin_amdgcn_rcpf(1.0f + e);
}
__device__ __forceinline__ float ftanh(float y) {
    float e2 = __expf(y + y);                   // inf-safe both ends
    return 1.0f - 2.0f * __builtin_amdgcn_rcpf(e2 + 1.0f);
}

// unpack 3 float4 (10 used) into named scalars dst0..dst9
#define U10(dst, q0, q1, q2) \
    const float dst##0=(q0).x, dst##1=(q0).y, dst##2=(q0).z, dst##3=(q0).w, \
                dst##4=(q1).x, dst##5=(q1).y, dst##6=(q1).z, dst##7=(q1).w, \
                dst##8=(q2).x, dst##9=(q2).y;

// one k-step: 15 independent FMAs (15 disjoint accumulator chains)
#define K15(k) \
    r0  = fmaf(wh0[0][k], a##k, r0);  z0  = fmaf(wh0[1][k], a##k, z0);  nh0 = fmaf(wh0[2][k], a##k, nh0); \
    ri1 = fmaf(wi1[0][k], a##k, ri1); zi1 = fmaf(wi1[1][k], a##k, zi1); nx1 = fmaf(wi1[2][k], a##k, nx1); \
    rh1 = fmaf(wh1[0][k], b##k, rh1); zh1 = fmaf(wh1[1][k], b##k, zh1); nh1 = fmaf(wh1[2][k], b##k, nh1); \
    ri2 = fmaf(wi2[0][k], b##k, ri2); zi2 = fmaf(wi2[1][k], b##k, zi2); nx2 = fmaf(wi2[2][k], b##k, nx2); \
    rh2 = fmaf(wh2[0][k], c##k, rh2); zh2 = fmaf(wh2[1][k], c##k, zh2); nh2 = fmaf(wh2[2][k], c##k, nh2);

// In-loop residency pin: zero-instruction opaque asm. Makes the value
// loop-carried through the asm -> the RA cannot re-materialize the global
// load inside the loop (R2-R7 evidence: without this, weights are re-read
// from L2 every iteration, ~800 stall cyc/iter invisible in VALUBusy).
#define PIN(v) asm volatile("" : "+v"(v))

__global__ __launch_bounds__(64)
__attribute__((amdgpu_waves_per_eu(1, 1)))   // occupancy target 1 wave/EU:
                                             // RA free to use up to 512 VGPRs
void gru3_pin(
    const float* __restrict__ x,
    const float* __restrict__ Wih0, const float* __restrict__ Whh0,
    const float* __restrict__ bih0, const float* __restrict__ bhh0,
    const float* __restrict__ Wih1, const float* __restrict__ Whh1,
    const float* __restrict__ bih1, const float* __restrict__ bhh1,
    const float* __restrict__ Wih2, const float* __restrict__ Whh2,
    const float* __restrict__ bih2, const float* __restrict__ bhh2,
    const float* __restrict__ Wout, const float* __restrict__ bout,
    float* __restrict__ out)
{
    __shared__ __align__(16) float lds[7 * STRIDE];

    const int lane  = threadIdx.x;     // block = 1 wave
    const int j     = lane % H_SZ;     // hidden unit 0..9
    const int g     = lane / H_SZ;     // group 0..6 (6 = dummy)
    const int b_raw = blockIdx.x * GPW + g;
    const int b     = b_raw < B_SZ ? b_raw : (B_SZ - 1);

    // ---- weights for this lane's unit j ----
    float wi0[3][I_SZ], wh0[3][H_SZ];
    float wi1[3][H_SZ], wh1[3][H_SZ];
    float wi2[3][H_SZ], wh2[3][H_SZ];
#pragma unroll
    for (int gg = 0; gg < 3; ++gg) {
        const int row = gg * H_SZ + j;
#pragma unroll
        for (int i = 0; i < I_SZ; ++i) wi0[gg][i] = Wih0[row * I_SZ + i];
#pragma unroll
        for (int k = 0; k < H_SZ; ++k) wh0[gg][k] = Whh0[row * H_SZ + k];
#pragma unroll
        for (int k = 0; k < H_SZ; ++k) wi1[gg][k] = Wih1[row * H_SZ + k];
#pragma unroll
        for (int k = 0; k < H_SZ; ++k) wh1[gg][k] = Whh1[row * H_SZ + k];
#pragma unroll
        for (int k = 0; k < H_SZ; ++k) wi2[gg][k] = Wih2[row * H_SZ + k];
#pragma unroll
        for (int k = 0; k < H_SZ; ++k) wh2[gg][k] = Whh2[row * H_SZ + k];
    }

    const float br0 = bih0[j] + bhh0[j], bz0 = bih0[H_SZ + j] + bhh0[H_SZ + j];
    const float bni0 = bih0[2 * H_SZ + j], bnh0 = bhh0[2 * H_SZ + j];
    const float br1 = bih1[j] + bhh1[j], bz1 = bih1[H_SZ + j] + bhh1[H_SZ + j];
    const float bni1 = bih1[2 * H_SZ + j], bnh1 = bhh1[2 * H_SZ + j];
    const float br2 = bih2[j] + bhh2[j], bz2 = bih2[H_SZ + j] + bhh2[H_SZ + j];
    const float bni2 = bih2[2 * H_SZ + j], bnh2 = bhh2[2 * H_SZ + j];

    const int gb = g * STRIDE;
    lds[gb + j]      = 0.0f;           // h0 slot
    lds[gb + 12 + j] = 0.0f;           // h1 slot
    lds[gb + 24 + j] = 0.0f;           // h2 slot
    float y0 = 0.0f, y1 = 0.0f, y2 = 0.0f;   // this lane's own h elements

    const float* xp = x + (size_t)b * (T_SZ * I_SZ);
    float cx0 = xp[0], cx1 = xp[1], cx2 = xp[2];   // x[t] for current iter

    const float4* pa = reinterpret_cast<const float4*>(&lds[gb]);
    const float4* pb = reinterpret_cast<const float4*>(&lds[gb + 12]);
    const float4* pc = reinterpret_cast<const float4*>(&lds[gb + 24]);

    float4 Aq0 = pa[0], Aq1 = pa[1], Aq2 = pa[2];   // h0(t-1)
    float4 Bq0 = pb[0], Bq1 = pb[1], Bq2 = pb[2];   // h1(t-2)
    float4 Cq0 = pc[0], Cq1 = pc[1], Cq2 = pc[2];   // h2(t-3)

    // iter it: L0@t=it, L1@t=it-1, L2@t=it-2 (layer-pipelined, barrier-free,
    // single wave). Dots run unconditionally; commits are branch-free selects.
#pragma unroll 1
    for (int it = 0; it < T_SZ + 2; ++it) {
        // ---- pin all 159 weights live-in-register at every iteration ----
#pragma unroll
        for (int gg = 0; gg < 3; ++gg) {
#pragma unroll
            for (int i = 0; i < I_SZ; ++i) PIN(wi0[gg][i]);
#pragma unroll
            for (int k = 0; k < H_SZ; ++k) {
                PIN(wh0[gg][k]); PIN(wi1[gg][k]); PIN(wh1[gg][k]);
                PIN(wi2[gg][k]); PIN(wh2[gg][k]);
            }
        }

        U10(a, Aq0, Aq1, Aq2)
        U10(b, Bq0, Bq1, Bq2)
        U10(c, Cq0, Cq1, Cq2)

        const float x0 = cx0, x1 = cx1, x2 = cx2;
        const int tn = (it + 1 < T_SZ) ? it + 1 : (T_SZ - 1);
        cx0 = xp[tn * 3 + 0];          // prefetch next x under this body
        cx1 = xp[tn * 3 + 1];
        cx2 = xp[tn * 3 + 2];

        // ---- 16 independent accumulator chains ----
        float r0 = br0, z0 = bz0, nx0 = bni0, nh0 = bnh0;
        float ri1 = br1, rh1 = 0.f, zi1 = bz1, zh1 = 0.f, nx1 = bni1, nh1 = bnh1;
        float ri2 = br2, rh2 = 0.f, zi2 = bz2, zh2 = 0.f, nx2 = bni2, nh2 = bnh2;

        r0  = fmaf(wi0[0][0], x0, r0);  r0  = fmaf(wi0[0][1], x1, r0);  r0  = fmaf(wi0[0][2], x2, r0);
        z0  = fmaf(wi0[1][0], x0, z0);  z0  = fmaf(wi0[1][1], x1, z0);  z0  = fmaf(wi0[1][2], x2, z0);
        nx0 = fmaf(wi0[2][0], x0, nx0); nx0 = fmaf(wi0[2][1], x1, nx0); nx0 = fmaf(wi0[2][2], x2, nx0);

        K15(0) K15(1) K15(2) K15(3) K15(4)
        K15(5) K15(6) K15(7) K15(8) K15(9)

        const float ar1 = ri1 + rh1, az1 = zi1 + zh1;
        const float ar2 = ri2 + rh2, az2 = zi2 + zh2;

        // ---- transcendental stage: 3 layers' chains independent ----
        const float R0 = fsig(r0),  Z0 = fsig(z0);
        const float R1 = fsig(ar1), Z1 = fsig(az1);
        const float R2 = fsig(ar2), Z2 = fsig(az2);
        const float N0 = ftanh(fmaf(R0, nh0, nx0));
        const float N1 = ftanh(fmaf(R1, nh1, nx1));
        const float N2 = ftanh(fmaf(R2, nh2, nx2));

        const float y0n = fmaf(Z0, y0 - N0, N0);
        const float y1n = fmaf(Z1, y1 - N1, N1);
        const float y2n = fmaf(Z2, y2 - N2, N2);

        // branch-free commit (inactive pipeline phases keep old h)
        y0 = (it < T_SZ)                 ? y0n : y0;
        y1 = (it >= 1 && it <= T_SZ)     ? y1n : y1;
        y2 = (it >= 2)                   ? y2n : y2;

        lds[gb + j]      = y0;
        lds[gb + 12 + j] = y1;
        lds[gb + 24 + j] = y2;

        // rotate: next iteration's h reads issue under the loop tail
        Aq0 = pa[0]; Aq1 = pa[1]; Aq2 = pa[2];
        Bq0 = pb[0]; Bq1 = pb[1]; Bq2 = pb[2];
        Cq0 = pc[0]; Cq1 = pc[1]; Cq2 = pc[2];
    }

    // ---- output projection: out[b] = h2(T-1) . Wout + bout ----
    if (j == 0 && g < GPW && b_raw < B_SZ) {
        const float* hv = &lds[gb + 24];
        float acc = bout[0];
#pragma unroll
        for (int k = 0; k < H_SZ; ++k) acc = fmaf(hv[k], Wout[k], acc);
        out[b_raw] = acc;
    }
}

extern "C" void kernel_launch(void* const* d_in, const int* in_sizes, int n_in,
                              void* d_out, int out_size, void* d_ws, size_t ws_size,
                              hipStream_t stream) {
    const float* x    = (const float*)d_in[0];
    const float* Wih0 = (const float*)d_in[1];
    const float* Whh0 = (const float*)d_in[2];
    const float* bih0 = (const float*)d_in[3];
    const float* bhh0 = (const float*)d_in[4];
    const float* Wih1 = (const float*)d_in[5];
    const float* Whh1 = (const float*)d_in[6];
    const float* bih1 = (const float*)d_in[7];
    const float* bhh1 = (const float*)d_in[8];
    const float* Wih2 = (const float*)d_in[9];
    const float* Whh2 = (const float*)d_in[10];
    const float* bih2 = (const float*)d_in[11];
    const float* bhh2 = (const float*)d_in[12];
    const float* Wout = (const float*)d_in[13];
    const float* bout = (const float*)d_in[14];
    float* out = (float*)d_out;

    const int grid = (B_SZ + GPW - 1) / GPW;   // 683 single-wave blocks
    gru3_pin<<<grid, 64, 0, stream>>>(x, Wih0, Whh0, bih0, bhh0,
                                      Wih1, Whh1, bih1, bhh1,
                                      Wih2, Whh2, bih2, bhh2,
                                      Wout, bout, out);
}

// Round 10
// 498.867 us; speedup vs baseline: 2.1093x; 1.2447x over previous
//
#include <hip/hip_runtime.h>
#include <cstdint>

#define B_SZ 4096
#define T_SZ 1000
#define I_SZ 3
#define H_SZ 10
#define GPW  6            // batch groups per wave (10 lanes each; lanes 60-63 dummy)
#define STRIDE 36         // words per group (3 slots x 12); 7 groups' float4 reads
                          // start at banks {0,4,8,...}: disjoint 4-bank spans.

typedef float v2f __attribute__((ext_vector_type(2)));
#define FMA2(w, h, acc) acc = __builtin_elementwise_fma((w), (h), (acc))  // v_pk_fma_f32

__device__ __forceinline__ float fsig(float s) {
    float e = __expf(-s);                       // s<<0 -> inf -> rcp 0; s>>0 -> 1
    return __builtin_amdgcn_rcpf(1.0f + e);
}
__device__ __forceinline__ float ftanh(float y) {
    float e2 = __expf(y + y);                   // inf-safe both ends
    return 1.0f - 2.0f * __builtin_amdgcn_rcpf(e2 + 1.0f);
}

// one packed k-step (pair p covers k=2p,2p+1): 15 independent v_pk_fma_f32
// over 15 disjoint float2 accumulator chains (depth 5 each)
#define PK15(p, ap, bp, cp) \
    FMA2(wh0p[0][p], ap, r0pk);  FMA2(wh0p[1][p], ap, z0pk);  FMA2(wh0p[2][p], ap, nh0pk); \
    FMA2(wi1p[0][p], ap, ri1);   FMA2(wi1p[1][p], ap, zi1);   FMA2(wi1p[2][p], ap, nx1pk); \
    FMA2(wh1p[0][p], bp, rh1);   FMA2(wh1p[1][p], bp, zh1);   FMA2(wh1p[2][p], bp, nh1pk); \
    FMA2(wi2p[0][p], bp, ri2);   FMA2(wi2p[1][p], bp, zi2);   FMA2(wi2p[2][p], bp, nx2pk); \
    FMA2(wh2p[0][p], cp, rh2);   FMA2(wh2p[1][p], cp, zh2);   FMA2(wh2p[2][p], cp, nh2pk);

__global__ __launch_bounds__(64, 1) void gru3_pk(
    const float* __restrict__ x,
    const float* __restrict__ Wih0, const float* __restrict__ Whh0,
    const float* __restrict__ bih0, const float* __restrict__ bhh0,
    const float* __restrict__ Wih1, const float* __restrict__ Whh1,
    const float* __restrict__ bih1, const float* __restrict__ bhh1,
    const float* __restrict__ Wih2, const float* __restrict__ Whh2,
    const float* __restrict__ bih2, const float* __restrict__ bhh2,
    const float* __restrict__ Wout, const float* __restrict__ bout,
    float* __restrict__ out)
{
    __shared__ __align__(16) float lds[7 * STRIDE];

    const int lane  = threadIdx.x;     // block = 1 wave
    const int j     = lane % H_SZ;     // hidden unit 0..9
    const int g     = lane / H_SZ;     // group 0..6 (6 = dummy)
    const int b_raw = blockIdx.x * GPW + g;
    const int b     = b_raw < B_SZ ? b_raw : (B_SZ - 1);

    // ---- weights for this lane's unit j, as float2 pairs (k even-aligned,
    // so the 8B global loads are aligned) ----
    float wi0[3][I_SZ];
    v2f wh0p[3][5], wi1p[3][5], wh1p[3][5], wi2p[3][5], wh2p[3][5];
#pragma unroll
    for (int gg = 0; gg < 3; ++gg) {
        const int row = gg * H_SZ + j;
#pragma unroll
        for (int i = 0; i < I_SZ; ++i) wi0[gg][i] = Wih0[row * I_SZ + i];
#pragma unroll
        for (int p = 0; p < 5; ++p) {
            wh0p[gg][p] = *reinterpret_cast<const v2f*>(&Whh0[row * H_SZ + 2 * p]);
            wi1p[gg][p] = *reinterpret_cast<const v2f*>(&Wih1[row * H_SZ + 2 * p]);
            wh1p[gg][p] = *reinterpret_cast<const v2f*>(&Whh1[row * H_SZ + 2 * p]);
            wi2p[gg][p] = *reinterpret_cast<const v2f*>(&Wih2[row * H_SZ + 2 * p]);
            wh2p[gg][p] = *reinterpret_cast<const v2f*>(&Whh2[row * H_SZ + 2 * p]);
        }
    }

    const float br0 = bih0[j] + bhh0[j], bz0 = bih0[H_SZ + j] + bhh0[H_SZ + j];
    const float bni0 = bih0[2 * H_SZ + j], bnh0 = bhh0[2 * H_SZ + j];
    const float br1 = bih1[j] + bhh1[j], bz1 = bih1[H_SZ + j] + bhh1[H_SZ + j];
    const float bni1 = bih1[2 * H_SZ + j], bnh1 = bhh1[2 * H_SZ + j];
    const float br2 = bih2[j] + bhh2[j], bz2 = bih2[H_SZ + j] + bhh2[H_SZ + j];
    const float bni2 = bih2[2 * H_SZ + j], bnh2 = bhh2[2 * H_SZ + j];

    const int gb = g * STRIDE;
    lds[gb + j]      = 0.0f;           // h0 slot
    lds[gb + 12 + j] = 0.0f;           // h1 slot
    lds[gb + 24 + j] = 0.0f;           // h2 slot
    float y0 = 0.0f, y1 = 0.0f, y2 = 0.0f;   // this lane's own h elements

    const float* xp = x + (size_t)b * (T_SZ * I_SZ);
    float cx0 = xp[0], cx1 = xp[1], cx2 = xp[2];   // x[t] for current iter

    const float4* pa = reinterpret_cast<const float4*>(&lds[gb]);
    const float4* pb = reinterpret_cast<const float4*>(&lds[gb + 12]);
    const float4* pc = reinterpret_cast<const float4*>(&lds[gb + 24]);

    float4 Aq0 = pa[0], Aq1 = pa[1], Aq2 = pa[2];   // h0(t-1)
    float4 Bq0 = pb[0], Bq1 = pb[1], Bq2 = pb[2];   // h1(t-2)
    float4 Cq0 = pc[0], Cq1 = pc[1], Cq2 = pc[2];   // h2(t-3)

    // iter it: L0@t=it, L1@t=it-1, L2@t=it-2 (layer-pipelined, barrier-free,
    // single wave). Dots run unconditionally; commits are branch-free selects.
#pragma unroll 1
    for (int it = 0; it < T_SZ + 2; ++it) {
        // h pairs for packed FMAs (pure register aliasing of the float4 reads)
        const v2f a0 = {Aq0.x, Aq0.y}, a1 = {Aq0.z, Aq0.w}, a2 = {Aq1.x, Aq1.y},
                  a3 = {Aq1.z, Aq1.w}, a4 = {Aq2.x, Aq2.y};
        const v2f b0 = {Bq0.x, Bq0.y}, b1 = {Bq0.z, Bq0.w}, b2 = {Bq1.x, Bq1.y},
                  b3 = {Bq1.z, Bq1.w}, b4 = {Bq2.x, Bq2.y};
        const v2f c0 = {Cq0.x, Cq0.y}, c1 = {Cq0.z, Cq0.w}, c2 = {Cq1.x, Cq1.y},
                  c3 = {Cq1.z, Cq1.w}, c4 = {Cq2.x, Cq2.y};

        const float x0 = cx0, x1 = cx1, x2 = cx2;
        const int tn = (it + 1 < T_SZ) ? it + 1 : (T_SZ - 1);
        cx0 = xp[tn * 3 + 0];          // prefetch next x under this body
        cx1 = xp[tn * 3 + 1];
        cx2 = xp[tn * 3 + 2];

        // ---- 15 packed + 3 scalar accumulator chains ----
        v2f r0pk = {0.f, 0.f}, z0pk = {0.f, 0.f}, nh0pk = {bnh0, 0.f};
        v2f ri1 = {br1, 0.f}, rh1 = {0.f, 0.f}, zi1 = {bz1, 0.f}, zh1 = {0.f, 0.f};
        v2f nx1pk = {bni1, 0.f}, nh1pk = {bnh1, 0.f};
        v2f ri2 = {br2, 0.f}, rh2 = {0.f, 0.f}, zi2 = {bz2, 0.f}, zh2 = {0.f, 0.f};
        v2f nx2pk = {bni2, 0.f}, nh2pk = {bnh2, 0.f};

        float xr0 = br0, xz0 = bz0, xn0 = bni0;    // L0 x-dot (scalar, depth 3)
        xr0 = fmaf(wi0[0][0], x0, xr0); xr0 = fmaf(wi0[0][1], x1, xr0); xr0 = fmaf(wi0[0][2], x2, xr0);
        xz0 = fmaf(wi0[1][0], x0, xz0); xz0 = fmaf(wi0[1][1], x1, xz0); xz0 = fmaf(wi0[1][2], x2, xz0);
        xn0 = fmaf(wi0[2][0], x0, xn0); xn0 = fmaf(wi0[2][1], x1, xn0); xn0 = fmaf(wi0[2][2], x2, xn0);

        PK15(0, a0, b0, c0)
        PK15(1, a1, b1, c1)
        PK15(2, a2, b2, c2)
        PK15(3, a3, b3, c3)
        PK15(4, a4, b4, c4)

        // ---- horizontal reduces (pk_add + scalar add) ----
        const float ar0 = xr0 + r0pk.x + r0pk.y;
        const float az0 = xz0 + z0pk.x + z0pk.y;
        const float hn0 = nh0pk.x + nh0pk.y;
        const v2f r1s = ri1 + rh1, z1s = zi1 + zh1;
        const v2f r2s = ri2 + rh2, z2s = zi2 + zh2;
        const float ar1 = r1s.x + r1s.y, az1 = z1s.x + z1s.y;
        const float ar2 = r2s.x + r2s.y, az2 = z2s.x + z2s.y;
        const float xn1 = nx1pk.x + nx1pk.y, hn1 = nh1pk.x + nh1pk.y;
        const float xn2 = nx2pk.x + nx2pk.y, hn2 = nh2pk.x + nh2pk.y;

        // ---- transcendental stage: 9 independent chains ----
        const float R0 = fsig(ar0), Z0 = fsig(az0);
        const float R1 = fsig(ar1), Z1 = fsig(az1);
        const float R2 = fsig(ar2), Z2 = fsig(az2);
        const float N0 = ftanh(fmaf(R0, hn0, xn0));
        const float N1 = ftanh(fmaf(R1, hn1, xn1));
        const float N2 = ftanh(fmaf(R2, hn2, xn2));

        const float y0n = fmaf(Z0, y0 - N0, N0);
        const float y1n = fmaf(Z1, y1 - N1, N1);
        const float y2n = fmaf(Z2, y2 - N2, N2);

        // branch-free commit (inactive pipeline phases keep old h)
        y0 = (it < T_SZ)                 ? y0n : y0;
        y1 = (it >= 1 && it <= T_SZ)     ? y1n : y1;
        y2 = (it >= 2)                   ? y2n : y2;

        lds[gb + j]      = y0;
        lds[gb + 12 + j] = y1;
        lds[gb + 24 + j] = y2;

        // rotate: next iteration's h reads issue under the loop tail
        Aq0 = pa[0]; Aq1 = pa[1]; Aq2 = pa[2];
        Bq0 = pb[0]; Bq1 = pb[1]; Bq2 = pb[2];
        Cq0 = pc[0]; Cq1 = pc[1]; Cq2 = pc[2];
    }

    // ---- output projection: out[b] = h2(T-1) . Wout + bout ----
    if (j == 0 && g < GPW && b_raw < B_SZ) {
        const float* hv = &lds[gb + 24];
        float acc = bout[0];
#pragma unroll
        for (int k = 0; k < H_SZ; ++k) acc = fmaf(hv[k], Wout[k], acc);
        out[b_raw] = acc;
    }
}

extern "C" void kernel_launch(void* const* d_in, const int* in_sizes, int n_in,
                              void* d_out, int out_size, void* d_ws, size_t ws_size,
                              hipStream_t stream) {
    const float* x    = (const float*)d_in[0];
    const float* Wih0 = (const float*)d_in[1];
    const float* Whh0 = (const float*)d_in[2];
    const float* bih0 = (const float*)d_in[3];
    const float* bhh0 = (const float*)d_in[4];
    const float* Wih1 = (const float*)d_in[5];
    const float* Whh1 = (const float*)d_in[6];
    const float* bih1 = (const float*)d_in[7];
    const float* bhh1 = (const float*)d_in[8];
    const float* Wih2 = (const float*)d_in[9];
    const float* Whh2 = (const float*)d_in[10];
    const float* bih2 = (const float*)d_in[11];
    const float* bhh2 = (const float*)d_in[12];
    const float* Wout = (const float*)d_in[13];
    const float* bout = (const float*)d_in[14];
    float* out = (float*)d_out;

    const int grid = (B_SZ + GPW - 1) / GPW;   // 683 single-wave blocks
    gru3_pk<<<grid, 64, 0, stream>>>(x, Wih0, Whh0, bih0, bhh0,
                                     Wih1, Whh1, bih1, bhh1,
                                     Wih2, Whh2, bih2, bhh2,
                                     Wout, bout, out);
}